// Round 11
// baseline (399.526 us; speedup 1.0000x reference)
//
#include <hip/hip_runtime.h>
#include <hip/hip_fp16.h>

// ---------------------------------------------------------------------------
// GCNEncoder: 3x GCNConv(128->128) + ReLU(2x) + global mean pool (64 graphs)
//   - CSR build, ZERO global atomics (two-level counting sort).
//   - dinv[src] folded into GEMM epilogue (xw' = dinv*xw) -> no normfix pass;
//     csr = 4B {src:u16, fp16(ew*dinv_dst)} finalized inside bucket_k.
//   - agg_k: R5-proven loop; nontemporal output stores keep xw resident in
//     per-XCD L2 during the gather (the structural bottleneck).
//   - GEMM via v_mfma_f32_16x16x32_f16, W split hi/lo, 512-thread blocks,
//     nontemporal A loads (A is dead after the read).
//   - NT builtins require clang ext_vector_type pointers (NOT HIP_vector_type
//     uint4/float4 — R10 compile lesson).
// ---------------------------------------------------------------------------

#define DFEAT 128
#define BLK_E 4096   // edges per sort block
#define NPART 8

typedef _Float16 half8 __attribute__((ext_vector_type(8)));
typedef float floatx4 __attribute__((ext_vector_type(4)));
typedef unsigned int uintx4 __attribute__((ext_vector_type(4)));

union u4h8 { uintx4 u; half8 h; };

__device__ __forceinline__ int wave_incl_scan(int v) {
    int incl = v;
    #pragma unroll
    for (int off = 1; off < 64; off <<= 1) {
        int u = __shfl_up(incl, (unsigned)off, 64);
        if ((int)(threadIdx.x & 63) >= off) incl += u;
    }
    return incl;
}

// K1: per-block histogram over coarse buckets (dst >> 8), bin-major output.
__global__ __launch_bounds__(256) void hist_k(const int* __restrict__ dst,
                                              int* __restrict__ hist,
                                              int E, int nblk, int nbuck) {
    __shared__ int h[256];
    int tid = threadIdx.x, b = blockIdx.x;
    h[tid] = 0;
    __syncthreads();
    int base = b * BLK_E;
    int nE = min(BLK_E, E - base);
    for (int i = tid; i < nE; i += 256) atomicAdd(&h[dst[base + i] >> 8], 1);
    __syncthreads();
    if (tid < nbuck) hist[tid * nblk + b] = h[tid];
}

// Block-local exclusive scan, 1024 elems/block, in-place; blksum = totals.
__global__ __launch_bounds__(256) void scanb_k(int* __restrict__ arr,
                                               int* __restrict__ blksum,
                                               int n_val, int n_scan) {
    int tid = threadIdx.x;
    int base = blockIdx.x * 1024 + tid * 4;
    int v0 = (base + 0 < n_val) ? arr[base + 0] : 0;
    int v1 = (base + 1 < n_val) ? arr[base + 1] : 0;
    int v2 = (base + 2 < n_val) ? arr[base + 2] : 0;
    int v3 = (base + 3 < n_val) ? arr[base + 3] : 0;
    int tsum = v0 + v1 + v2 + v3;
    int incl = wave_incl_scan(tsum);
    __shared__ int wtot[4];
    if ((tid & 63) == 63) wtot[tid >> 6] = incl;
    __syncthreads();
    int woff = 0;
    for (int w = 0; w < (tid >> 6); w++) woff += wtot[w];
    int texcl = woff + incl - tsum;
    if (base + 0 < n_scan) arr[base + 0] = texcl;
    if (base + 1 < n_scan) arr[base + 1] = texcl + v0;
    if (base + 2 < n_scan) arr[base + 2] = texcl + v0 + v1;
    if (base + 3 < n_scan) arr[base + 3] = texcl + v0 + v1 + v2;
    if (tid == 255) blksum[blockIdx.x] = woff + incl;
}

__global__ __launch_bounds__(256) void scan_small256(int* __restrict__ blksum, int nb) {
    int tid = threadIdx.x;
    int v = (tid < nb) ? blksum[tid] : 0;
    int incl = wave_incl_scan(v);
    __shared__ int wtot[4];
    if ((tid & 63) == 63) wtot[tid >> 6] = incl;
    __syncthreads();
    int woff = 0;
    for (int w = 0; w < (tid >> 6); w++) woff += wtot[w];
    if (tid < nb) blksum[tid] = woff + incl - v;
}

// K3: scatter edges into bucket-grouped array, coalesced via LDS sort.
// rec = {src | dstlow<<16, ew_bits}. Requires N <= 65536.
__global__ __launch_bounds__(256) void scat_k(const int* __restrict__ src,
                                              const int* __restrict__ dst,
                                              const float* __restrict__ ew,
                                              const int* __restrict__ offs,
                                              const int* __restrict__ blksum,
                                              uint2* __restrict__ rec,
                                              int E, int nblk, int nbuck) {
    __shared__ int lcur[256];
    __shared__ int gbase[256];
    __shared__ uint2 srec[BLK_E];
    __shared__ int gpos[BLK_E];
    int tid = threadIdx.x, b = blockIdx.x;
    lcur[tid] = 0;
    __syncthreads();
    int base = b * BLK_E;
    int nE = min(BLK_E, E - base);
    for (int i = tid; i < nE; i += 256) atomicAdd(&lcur[dst[base + i] >> 8], 1);
    __syncthreads();
    int v = lcur[tid];
    int incl = wave_incl_scan(v);
    __shared__ int wtot[4];
    if ((tid & 63) == 63) wtot[tid >> 6] = incl;
    __syncthreads();
    int woff = 0;
    for (int w = 0; w < (tid >> 6); w++) woff += wtot[w];
    int excl = woff + incl - v;
    __syncthreads();
    lcur[tid] = excl;
    int oidx = tid * nblk + b;
    gbase[tid] = (tid < nbuck) ? (offs[oidx] + blksum[oidx >> 10] - excl) : 0;
    __syncthreads();
    for (int i = tid; i < nE; i += 256) {
        int e = base + i;
        int d = dst[e];
        int bin = d >> 8;
        int slot = atomicAdd(&lcur[bin], 1);
        uint2 r;
        r.x = (unsigned)src[e] | ((unsigned)(d & 255) << 16);
        r.y = __float_as_uint(ew[e]);
        srec[slot] = r;
        gpos[slot] = gbase[bin] + slot;
    }
    __syncthreads();
    for (int i = tid; i < nE; i += 256) rec[gpos[i]] = srec[i];
}

// K4: one block per 256-node bucket. Per-(node, src>>13) counts + fixed-point
// deg in LDS, 2048-wide scan -> rp8 segment offsets + dinv, then place FINAL
// 4B CSR entries {src:u16, fp16(ew*dinv_dst)} grouped by src partition.
// (dinv[src] is folded into xw by the GEMM epilogue -> no normfix pass.)
__global__ __launch_bounds__(1024) void bucket_k(const uint2* __restrict__ rec,
                                                 const int* __restrict__ offs,
                                                 const int* __restrict__ blksum,
                                                 float* __restrict__ dinv,
                                                 int* __restrict__ rp8,
                                                 unsigned* __restrict__ csr,
                                                 int N, int nblk) {
    __shared__ int cnt[2048];       // key = dl*8 + (src>>13)
    __shared__ unsigned degfx[256];
    __shared__ int cur[2048];
    __shared__ int wtot[16];
    int tid = threadIdx.x, bin = blockIdx.x;
    int idx0 = bin * nblk, idx1 = (bin + 1) * nblk;
    int start = offs[idx0] + blksum[idx0 >> 10];
    int endp  = offs[idx1] + blksum[idx1 >> 10];  // sentinel -> E for last bin
    cnt[tid] = 0; cnt[tid + 1024] = 0;
    if (tid < 256) degfx[tid] = 0;
    __syncthreads();
    for (int i = start + tid; i < endp; i += 1024) {
        uint2 r = rec[i];
        int dl = (r.x >> 16) & 255;
        int part = (r.x & 0xffff) >> 13;
        atomicAdd(&cnt[dl * NPART + part], 1);
        atomicAdd(&degfx[dl], (unsigned)(__uint_as_float(r.y) * 1048576.0f + 0.5f));
    }
    __syncthreads();
    int v0 = cnt[tid * 2], v1 = cnt[tid * 2 + 1];
    int tsum = v0 + v1;
    int incl = wave_incl_scan(tsum);
    if ((tid & 63) == 63) wtot[tid >> 6] = incl;
    __syncthreads();
    int woff = 0;
    for (int w = 0; w < (tid >> 6); w++) woff += wtot[w];
    int texcl = woff + incl - tsum;
    cur[tid * 2] = texcl;
    cur[tid * 2 + 1] = texcl + v0;
    // nodes >= N in the tail bucket have zero counts -> their rp8 slots get
    // the bucket end offset, which serves as the sentinel for node N-1.
    rp8[bin * 2048 + tid * 2] = start + texcl;
    rp8[bin * 2048 + tid * 2 + 1] = start + texcl + v0;
    __syncthreads();
    if (tid < 256) {
        int node = bin * 256 + tid;
        if (node < N) {
            float deg = (float)degfx[tid] * (1.0f / 1048576.0f) + 1.0f;
            float di = rsqrtf(deg);
            dinv[node] = di;
            degfx[tid] = __float_as_uint(di);   // stash dinv
        }
    }
    __syncthreads();
    for (int i = start + tid; i < endp; i += 1024) {
        uint2 r = rec[i];
        int dl = (r.x >> 16) & 255;
        int s = r.x & 0xffff;
        int part = s >> 13;
        int p = start + atomicAdd(&cur[dl * NPART + part], 1);
        float di_d = __uint_as_float(degfx[dl]);
        float nm = __uint_as_float(r.y) * di_d;   // ew * dinv_dst (final)
        unsigned h = (unsigned)__half_as_ushort(__float2half_rn(nm));
        csr[p] = (unsigned)s | (h << 16);
    }
}

// W[3] fp32 -> swizzled fp16 hi/lo in MFMA B-fragment order.
__global__ void wconv_k(const float* __restrict__ W0, const float* __restrict__ W1,
                        const float* __restrict__ W2, _Float16* __restrict__ Wsw) {
    int idx = blockIdx.x * 256 + threadIdx.x;
    if (idx >= 3 * 128 * 128) return;
    int w = idx >> 14;
    int r = idx & 16383;
    int k = r >> 7, nn = r & 127;
    const float* W = (w == 0) ? W0 : (w == 1) ? W1 : W2;
    float v = W[k * 128 + nn];
    _Float16 hi = (_Float16)v;
    _Float16 lo = (_Float16)((v - (float)hi) * 1024.0f);
    int kk = k >> 5, quad = (k >> 3) & 3, j = k & 7;
    int t = nn >> 4, L = quad * 16 + (nn & 15);
    int off = ((kk * 8 + t) * 64 + L) * 8 + j;
    Wsw[(size_t)(w * 2 + 0) * 16384 + off] = hi;
    Wsw[(size_t)(w * 2 + 1) * 16384 + off] = lo;
}

// MFMA GEMM core (A fp16, NT loads). Epilogue scales row by dinv[row]:
// C[i] = dinv[i] * (A[i] @ W). Block: 8 waves, 128 rows.
__global__ __launch_bounds__(512) void gemm_mfma(const _Float16* __restrict__ A,
                                                 const _Float16* __restrict__ Wsw,
                                                 const float* __restrict__ dinv,
                                                 _Float16* __restrict__ C, int n) {
    __shared__ _Float16 Bl[2 * 16384];
    {
        const uint4* s = (const uint4*)Wsw;
        uint4* d = (uint4*)Bl;
        for (int i = threadIdx.x; i < 4096; i += 512) d[i] = s[i];
    }
    int wave = threadIdx.x >> 6, lane = threadIdx.x & 63;
    int quad = lane >> 4, mcol = lane & 15;
    int row0 = blockIdx.x * 128 + wave * 16 + mcol;
    half8 af[4] = {};
    if (row0 < n) {
        const uintx4* Arow = (const uintx4*)(A + (size_t)row0 * DFEAT);
        u4h8 t0, t1, t2, t3;
        t0.u = __builtin_nontemporal_load(&Arow[0 + quad]);
        t1.u = __builtin_nontemporal_load(&Arow[4 + quad]);
        t2.u = __builtin_nontemporal_load(&Arow[8 + quad]);
        t3.u = __builtin_nontemporal_load(&Arow[12 + quad]);
        af[0] = t0.h; af[1] = t1.h; af[2] = t2.h; af[3] = t3.h;
    }
    __syncthreads();
    floatx4 acch[8] = {};
    floatx4 accl[8] = {};
    const half8* Bh = (const half8*)Bl;
    const half8* Blo = (const half8*)(Bl + 16384);
    #pragma unroll
    for (int kk = 0; kk < 4; kk++) {
        #pragma unroll
        for (int t = 0; t < 8; t++) {
            half8 bh = Bh[(kk * 8 + t) * 64 + lane];
            acch[t] = __builtin_amdgcn_mfma_f32_16x16x32_f16(af[kk], bh, acch[t], 0, 0, 0);
            half8 bl = Blo[(kk * 8 + t) * 64 + lane];
            accl[t] = __builtin_amdgcn_mfma_f32_16x16x32_f16(af[kk], bl, accl[t], 0, 0, 0);
        }
    }
    int orow_base = blockIdx.x * 128 + wave * 16 + quad * 4;
    float dv[4];
    #pragma unroll
    for (int r = 0; r < 4; r++)
        dv[r] = (orow_base + r < n) ? dinv[orow_base + r] : 0.f;
    #pragma unroll
    for (int t = 0; t < 8; t++) {
        #pragma unroll
        for (int r = 0; r < 4; r++) {
            int orow = orow_base + r;
            if (orow < n) {
                float v = (acch[t][r] + accl[t][r] * (1.0f / 1024.0f)) * dv[r];
                C[(size_t)orow * DFEAT + t * 16 + mcol] = (_Float16)v;
            }
        }
    }
}

// Same, but reads fp32 A (layer 0: x directly).
__global__ __launch_bounds__(512) void gemm_mfma_f32(const float* __restrict__ A,
                                                     const _Float16* __restrict__ Wsw,
                                                     const float* __restrict__ dinv,
                                                     _Float16* __restrict__ C, int n) {
    __shared__ _Float16 Bl[2 * 16384];
    {
        const uint4* s = (const uint4*)Wsw;
        uint4* d = (uint4*)Bl;
        for (int i = threadIdx.x; i < 4096; i += 512) d[i] = s[i];
    }
    int wave = threadIdx.x >> 6, lane = threadIdx.x & 63;
    int quad = lane >> 4, mcol = lane & 15;
    int row0 = blockIdx.x * 128 + wave * 16 + mcol;
    half8 af[4] = {};
    if (row0 < n) {
        const floatx4* Arow = (const floatx4*)(A + (size_t)row0 * DFEAT);
        #pragma unroll
        for (int kk = 0; kk < 4; kk++) {
            floatx4 f0 = __builtin_nontemporal_load(&Arow[kk * 8 + quad * 2]);
            floatx4 f1 = __builtin_nontemporal_load(&Arow[kk * 8 + quad * 2 + 1]);
            half8 a;
            a[0] = (_Float16)f0[0]; a[1] = (_Float16)f0[1];
            a[2] = (_Float16)f0[2]; a[3] = (_Float16)f0[3];
            a[4] = (_Float16)f1[0]; a[5] = (_Float16)f1[1];
            a[6] = (_Float16)f1[2]; a[7] = (_Float16)f1[3];
            af[kk] = a;
        }
    }
    __syncthreads();
    floatx4 acch[8] = {};
    floatx4 accl[8] = {};
    const half8* Bh = (const half8*)Bl;
    const half8* Blo = (const half8*)(Bl + 16384);
    #pragma unroll
    for (int kk = 0; kk < 4; kk++) {
        #pragma unroll
        for (int t = 0; t < 8; t++) {
            half8 bh = Bh[(kk * 8 + t) * 64 + lane];
            acch[t] = __builtin_amdgcn_mfma_f32_16x16x32_f16(af[kk], bh, acch[t], 0, 0, 0);
            half8 bl = Blo[(kk * 8 + t) * 64 + lane];
            accl[t] = __builtin_amdgcn_mfma_f32_16x16x32_f16(af[kk], bl, accl[t], 0, 0, 0);
        }
    }
    int orow_base = blockIdx.x * 128 + wave * 16 + quad * 4;
    float dv[4];
    #pragma unroll
    for (int r = 0; r < 4; r++)
        dv[r] = (orow_base + r < n) ? dinv[orow_base + r] : 0.f;
    #pragma unroll
    for (int t = 0; t < 8; t++) {
        #pragma unroll
        for (int r = 0; r < 4; r++) {
            int orow = orow_base + r;
            if (orow < n) {
                float v = (acch[t][r] + accl[t][r] * (1.0f / 1024.0f)) * dv[r];
                C[(size_t)orow * DFEAT + t * 16 + mcol] = (_Float16)v;
            }
        }
    }
}

// 4 nodes per 256-thread block (one wave each); lane holds 2 fp16 features.
// xw is pre-scaled by dinv (gemm epilogue): msg = (ew*dinv_d) * xw'[src];
// self term = dinv_d * xw'[node]. Output stores are NONTEMPORAL so the
// write stream doesn't evict xw from per-XCD L2 during the gather.
__global__ __launch_bounds__(256) void agg_k(const __half2* __restrict__ xw2,
                                             const int* __restrict__ rp8,
                                             const unsigned* __restrict__ csr,
                                             const float* __restrict__ dinv,
                                             const float* __restrict__ bias,
                                             __half2* __restrict__ out, int relu, int n) {
    int node = blockIdx.x * 4 + (threadIdx.x >> 6);
    if (node >= n) return;
    int lane = threadIdx.x & 63;
    float di = dinv[node];
    float2 selfv = __half22float2(xw2[(size_t)node * 64 + lane]);
    float ax = di * selfv.x, ay = di * selfv.y;
    int e = rp8[node * NPART], end = rp8[node * NPART + NPART];
    for (; e + 4 <= end; e += 4) {
        unsigned c0 = csr[e + 0], c1 = csr[e + 1];
        unsigned c2 = csr[e + 2], c3 = csr[e + 3];
        float2 v0 = __half22float2(xw2[(size_t)(c0 & 0xffff) * 64 + lane]);
        float2 v1 = __half22float2(xw2[(size_t)(c1 & 0xffff) * 64 + lane]);
        float2 v2 = __half22float2(xw2[(size_t)(c2 & 0xffff) * 64 + lane]);
        float2 v3 = __half22float2(xw2[(size_t)(c3 & 0xffff) * 64 + lane]);
        float w0 = __half2float(__ushort_as_half((unsigned short)(c0 >> 16)));
        float w1 = __half2float(__ushort_as_half((unsigned short)(c1 >> 16)));
        float w2 = __half2float(__ushort_as_half((unsigned short)(c2 >> 16)));
        float w3 = __half2float(__ushort_as_half((unsigned short)(c3 >> 16)));
        ax = fmaf(w0, v0.x, ax); ay = fmaf(w0, v0.y, ay);
        ax = fmaf(w1, v1.x, ax); ay = fmaf(w1, v1.y, ay);
        ax = fmaf(w2, v2.x, ax); ay = fmaf(w2, v2.y, ay);
        ax = fmaf(w3, v3.x, ax); ay = fmaf(w3, v3.y, ay);
    }
    for (; e < end; e++) {
        unsigned c = csr[e];
        float w = __half2float(__ushort_as_half((unsigned short)(c >> 16)));
        float2 v = __half22float2(xw2[(size_t)(c & 0xffff) * 64 + lane]);
        ax = fmaf(w, v.x, ax); ay = fmaf(w, v.y, ay);
    }
    float2 bv = ((const float2*)bias)[lane];
    ax += bv.x; ay += bv.y;
    if (relu) { ax = fmaxf(ax, 0.f); ay = fmaxf(ay, 0.f); }
    __half2 o = __floats2half2_rn(ax, ay);
    __builtin_nontemporal_store(*(unsigned*)&o,
                                (unsigned*)&out[(size_t)node * 64 + lane]);
}

// batch is sorted: chunk of 64 nodes per block, 128 threads (one per feature).
__global__ __launch_bounds__(128) void pool_k(const __half* __restrict__ h,
                                              const int* __restrict__ batch,
                                              float* __restrict__ out,
                                              float* __restrict__ pool_cnt, int n) {
    int j = threadIdx.x;
    int start = blockIdx.x * 64;
    if (start >= n) return;
    int end = start + 64; if (end > n) end = n;
    int g = batch[start];
    float acc = 0.f;
    float ccnt = 0.f;
    for (int i = start; i < end; i++) {
        int bi = batch[i];
        if (bi != g) {
            atomicAdd(&out[g * DFEAT + j], acc);
            if (j == 0) atomicAdd(&pool_cnt[g], ccnt);
            acc = 0.f; ccnt = 0.f; g = bi;
        }
        unsigned short u = __builtin_nontemporal_load(
            (const unsigned short*)&h[(size_t)i * DFEAT + j]);
        acc += __half2float(__ushort_as_half(u));
        ccnt += 1.f;
    }
    atomicAdd(&out[g * DFEAT + j], acc);
    if (j == 0) atomicAdd(&pool_cnt[g], ccnt);
}

__global__ void div_k(float* __restrict__ out, const float* __restrict__ cnt) {
    int idx = blockIdx.x * 256 + threadIdx.x;
    if (idx < 64 * DFEAT) {
        float c = cnt[idx >> 7];
        out[idx] = out[idx] / fmaxf(c, 1.0f);
    }
}

extern "C" void kernel_launch(void* const* d_in, const int* in_sizes, int n_in,
                              void* d_out, int out_size, void* d_ws, size_t ws_size,
                              hipStream_t stream) {
    const float* x    = (const float*)d_in[0];
    const int*  eidx  = (const int*)d_in[1];
    const float* ew   = (const float*)d_in[2];
    const int*  batch = (const int*)d_in[3];
    const float* W0 = (const float*)d_in[4];
    const float* b0 = (const float*)d_in[5];
    const float* W1 = (const float*)d_in[6];
    const float* b1 = (const float*)d_in[7];
    const float* W2 = (const float*)d_in[8];
    const float* b2 = (const float*)d_in[9];
    float* out = (float*)d_out;

    const int N = in_sizes[0] / DFEAT;   // 50000 (must be <= 65536)
    const int E = in_sizes[2];           // 1600000
    const int* src = eidx;
    const int* dst = eidx + E;

    const int nbuck = (N + 255) / 256;           // 196
    const int nblk  = (E + BLK_E - 1) / BLK_E;   // 391
    const int total = nbuck * nblk;
    const int n_scan = total + 1;                // sentinel -> E

    size_t off = 0;
    auto walloc = [&](size_t bytes) -> void* {
        void* p = (char*)d_ws + off;
        off += (bytes + 255) & ~(size_t)255;
        return p;
    };
    float*   dinv    = (float*)  walloc((size_t)N * 4);
    int*     rp8     = (int*)    walloc(((size_t)nbuck * 2048 + 8) * 4);
    int*     offs    = (int*)    walloc((size_t)n_scan * 4);
    int*     blksum  = (int*)    walloc(256 * 4);
    uint2*   rec     = (uint2*)  walloc((size_t)E * 8);
    unsigned* csr    = (unsigned*)walloc((size_t)E * 4);
    _Float16* xwH    = (_Float16*)walloc((size_t)N * DFEAT * 2);
    _Float16* hH     = (_Float16*)walloc((size_t)N * DFEAT * 2);
    _Float16* Wsw    = (_Float16*)walloc((size_t)6 * 16384 * 2);
    float*   pool_cnt= (float*)  walloc(64 * 4);

    (void)hipMemsetAsync(out, 0, (size_t)64 * DFEAT * 4, stream);
    (void)hipMemsetAsync(pool_cnt, 0, 64 * 4, stream);

    // ---- CSR build (no global atomics, no normfix) ----
    hist_k<<<nblk, 256, 0, stream>>>(dst, offs, E, nblk, nbuck);
    int nsb = (n_scan + 1023) / 1024;
    scanb_k<<<nsb, 256, 0, stream>>>(offs, blksum, total, n_scan);
    scan_small256<<<1, 256, 0, stream>>>(blksum, nsb);
    scat_k<<<nblk, 256, 0, stream>>>(src, dst, ew, offs, blksum, rec, E, nblk, nbuck);
    bucket_k<<<nbuck, 1024, 0, stream>>>(rec, offs, blksum, dinv, rp8, csr, N, nblk);

    wconv_k<<<(3 * 16384 + 255) / 256, 256, 0, stream>>>(W0, W1, W2, Wsw);

    int gG = (N + 127) / 128;
    int gA = (N + 3) / 4;
    // layer 0 (reads fp32 x directly)
    gemm_mfma_f32<<<gG, 512, 0, stream>>>(x, Wsw + (size_t)0 * 32768, dinv, xwH, N);
    agg_k<<<gA, 256, 0, stream>>>((const __half2*)xwH, rp8, csr, dinv, b0,
                                  (__half2*)hH, 1, N);
    // layer 1
    gemm_mfma<<<gG, 512, 0, stream>>>(hH, Wsw + (size_t)1 * 32768, dinv, xwH, N);
    agg_k<<<gA, 256, 0, stream>>>((const __half2*)xwH, rp8, csr, dinv, b1,
                                  (__half2*)hH, 1, N);
    // layer 2
    gemm_mfma<<<gG, 512, 0, stream>>>(hH, Wsw + (size_t)2 * 32768, dinv, xwH, N);
    agg_k<<<gA, 256, 0, stream>>>((const __half2*)xwH, rp8, csr, dinv, b2,
                                  (__half2*)hH, 0, N);

    pool_k<<<(N + 63) / 64, 128, 0, stream>>>((const __half*)hH, batch, out, pool_cnt, N);
    div_k<<<32, 256, 0, stream>>>(out, pool_cnt);
}

// Round 12
// 387.822 us; speedup vs baseline: 1.0302x; 1.0302x over previous
//
#include <hip/hip_runtime.h>
#include <hip/hip_fp16.h>

// ---------------------------------------------------------------------------
// GCNEncoder: 3x GCNConv(128->128) + ReLU(2x) + global mean pool (64 graphs)
//   - CSR build, ZERO global atomics (two-level counting sort).
//   - dinv[src] folded into GEMM epilogue (xw' = dinv*xw) -> no normfix pass;
//     csr = 4B {src:u16, fp16(ew*dinv_dst)} finalized inside bucket_k.
//   - agg_k: R5-proven loop (at the L2-miss/fabric service floor: FETCH
//     ~1.4x the 8-XCD compulsory read; R6/R8/R11 attack vectors all neutral).
//   - NO nontemporal hints: R11 showed they evict the producer->consumer
//     activation stream from L2 and cost ~28 µs net.
//   - GEMM via v_mfma_f32_16x16x32_f16, W split hi/lo, 512-thread blocks.
// ---------------------------------------------------------------------------

#define DFEAT 128
#define BLK_E 4096   // edges per sort block
#define NPART 8

typedef _Float16 half8 __attribute__((ext_vector_type(8)));
typedef float floatx4 __attribute__((ext_vector_type(4)));

__device__ __forceinline__ int wave_incl_scan(int v) {
    int incl = v;
    #pragma unroll
    for (int off = 1; off < 64; off <<= 1) {
        int u = __shfl_up(incl, (unsigned)off, 64);
        if ((int)(threadIdx.x & 63) >= off) incl += u;
    }
    return incl;
}

// K1: per-block histogram over coarse buckets (dst >> 8), bin-major output.
__global__ __launch_bounds__(256) void hist_k(const int* __restrict__ dst,
                                              int* __restrict__ hist,
                                              int E, int nblk, int nbuck) {
    __shared__ int h[256];
    int tid = threadIdx.x, b = blockIdx.x;
    h[tid] = 0;
    __syncthreads();
    int base = b * BLK_E;
    int nE = min(BLK_E, E - base);
    for (int i = tid; i < nE; i += 256) atomicAdd(&h[dst[base + i] >> 8], 1);
    __syncthreads();
    if (tid < nbuck) hist[tid * nblk + b] = h[tid];
}

// Block-local exclusive scan, 1024 elems/block, in-place; blksum = totals.
__global__ __launch_bounds__(256) void scanb_k(int* __restrict__ arr,
                                               int* __restrict__ blksum,
                                               int n_val, int n_scan) {
    int tid = threadIdx.x;
    int base = blockIdx.x * 1024 + tid * 4;
    int v0 = (base + 0 < n_val) ? arr[base + 0] : 0;
    int v1 = (base + 1 < n_val) ? arr[base + 1] : 0;
    int v2 = (base + 2 < n_val) ? arr[base + 2] : 0;
    int v3 = (base + 3 < n_val) ? arr[base + 3] : 0;
    int tsum = v0 + v1 + v2 + v3;
    int incl = wave_incl_scan(tsum);
    __shared__ int wtot[4];
    if ((tid & 63) == 63) wtot[tid >> 6] = incl;
    __syncthreads();
    int woff = 0;
    for (int w = 0; w < (tid >> 6); w++) woff += wtot[w];
    int texcl = woff + incl - tsum;
    if (base + 0 < n_scan) arr[base + 0] = texcl;
    if (base + 1 < n_scan) arr[base + 1] = texcl + v0;
    if (base + 2 < n_scan) arr[base + 2] = texcl + v0 + v1;
    if (base + 3 < n_scan) arr[base + 3] = texcl + v0 + v1 + v2;
    if (tid == 255) blksum[blockIdx.x] = woff + incl;
}

__global__ __launch_bounds__(256) void scan_small256(int* __restrict__ blksum, int nb) {
    int tid = threadIdx.x;
    int v = (tid < nb) ? blksum[tid] : 0;
    int incl = wave_incl_scan(v);
    __shared__ int wtot[4];
    if ((tid & 63) == 63) wtot[tid >> 6] = incl;
    __syncthreads();
    int woff = 0;
    for (int w = 0; w < (tid >> 6); w++) woff += wtot[w];
    if (tid < nb) blksum[tid] = woff + incl - v;
}

// K3: scatter edges into bucket-grouped array, coalesced via LDS sort.
// rec = {src | dstlow<<16, ew_bits}. Requires N <= 65536.
__global__ __launch_bounds__(256) void scat_k(const int* __restrict__ src,
                                              const int* __restrict__ dst,
                                              const float* __restrict__ ew,
                                              const int* __restrict__ offs,
                                              const int* __restrict__ blksum,
                                              uint2* __restrict__ rec,
                                              int E, int nblk, int nbuck) {
    __shared__ int lcur[256];
    __shared__ int gbase[256];
    __shared__ uint2 srec[BLK_E];
    __shared__ int gpos[BLK_E];
    int tid = threadIdx.x, b = blockIdx.x;
    lcur[tid] = 0;
    __syncthreads();
    int base = b * BLK_E;
    int nE = min(BLK_E, E - base);
    for (int i = tid; i < nE; i += 256) atomicAdd(&lcur[dst[base + i] >> 8], 1);
    __syncthreads();
    int v = lcur[tid];
    int incl = wave_incl_scan(v);
    __shared__ int wtot[4];
    if ((tid & 63) == 63) wtot[tid >> 6] = incl;
    __syncthreads();
    int woff = 0;
    for (int w = 0; w < (tid >> 6); w++) woff += wtot[w];
    int excl = woff + incl - v;
    __syncthreads();
    lcur[tid] = excl;
    int oidx = tid * nblk + b;
    gbase[tid] = (tid < nbuck) ? (offs[oidx] + blksum[oidx >> 10] - excl) : 0;
    __syncthreads();
    for (int i = tid; i < nE; i += 256) {
        int e = base + i;
        int d = dst[e];
        int bin = d >> 8;
        int slot = atomicAdd(&lcur[bin], 1);
        uint2 r;
        r.x = (unsigned)src[e] | ((unsigned)(d & 255) << 16);
        r.y = __float_as_uint(ew[e]);
        srec[slot] = r;
        gpos[slot] = gbase[bin] + slot;
    }
    __syncthreads();
    for (int i = tid; i < nE; i += 256) rec[gpos[i]] = srec[i];
}

// K4: one block per 256-node bucket. Per-(node, src>>13) counts + fixed-point
// deg in LDS, 2048-wide scan -> rp8 segment offsets + dinv, then place FINAL
// 4B CSR entries {src:u16, fp16(ew*dinv_dst)} grouped by src partition.
__global__ __launch_bounds__(1024) void bucket_k(const uint2* __restrict__ rec,
                                                 const int* __restrict__ offs,
                                                 const int* __restrict__ blksum,
                                                 float* __restrict__ dinv,
                                                 int* __restrict__ rp8,
                                                 unsigned* __restrict__ csr,
                                                 int N, int nblk) {
    __shared__ int cnt[2048];       // key = dl*8 + (src>>13)
    __shared__ unsigned degfx[256];
    __shared__ int cur[2048];
    __shared__ int wtot[16];
    int tid = threadIdx.x, bin = blockIdx.x;
    int idx0 = bin * nblk, idx1 = (bin + 1) * nblk;
    int start = offs[idx0] + blksum[idx0 >> 10];
    int endp  = offs[idx1] + blksum[idx1 >> 10];  // sentinel -> E for last bin
    cnt[tid] = 0; cnt[tid + 1024] = 0;
    if (tid < 256) degfx[tid] = 0;
    __syncthreads();
    for (int i = start + tid; i < endp; i += 1024) {
        uint2 r = rec[i];
        int dl = (r.x >> 16) & 255;
        int part = (r.x & 0xffff) >> 13;
        atomicAdd(&cnt[dl * NPART + part], 1);
        atomicAdd(&degfx[dl], (unsigned)(__uint_as_float(r.y) * 1048576.0f + 0.5f));
    }
    __syncthreads();
    int v0 = cnt[tid * 2], v1 = cnt[tid * 2 + 1];
    int tsum = v0 + v1;
    int incl = wave_incl_scan(tsum);
    if ((tid & 63) == 63) wtot[tid >> 6] = incl;
    __syncthreads();
    int woff = 0;
    for (int w = 0; w < (tid >> 6); w++) woff += wtot[w];
    int texcl = woff + incl - tsum;
    cur[tid * 2] = texcl;
    cur[tid * 2 + 1] = texcl + v0;
    // nodes >= N in the tail bucket have zero counts -> their rp8 slots get
    // the bucket end offset, which serves as the sentinel for node N-1.
    rp8[bin * 2048 + tid * 2] = start + texcl;
    rp8[bin * 2048 + tid * 2 + 1] = start + texcl + v0;
    __syncthreads();
    if (tid < 256) {
        int node = bin * 256 + tid;
        if (node < N) {
            float deg = (float)degfx[tid] * (1.0f / 1048576.0f) + 1.0f;
            float di = rsqrtf(deg);
            dinv[node] = di;
            degfx[tid] = __float_as_uint(di);   // stash dinv
        }
    }
    __syncthreads();
    for (int i = start + tid; i < endp; i += 1024) {
        uint2 r = rec[i];
        int dl = (r.x >> 16) & 255;
        int s = r.x & 0xffff;
        int part = s >> 13;
        int p = start + atomicAdd(&cur[dl * NPART + part], 1);
        float di_d = __uint_as_float(degfx[dl]);
        float nm = __uint_as_float(r.y) * di_d;   // ew * dinv_dst (final)
        unsigned h = (unsigned)__half_as_ushort(__float2half_rn(nm));
        csr[p] = (unsigned)s | (h << 16);
    }
}

// W[3] fp32 -> swizzled fp16 hi/lo in MFMA B-fragment order.
__global__ void wconv_k(const float* __restrict__ W0, const float* __restrict__ W1,
                        const float* __restrict__ W2, _Float16* __restrict__ Wsw) {
    int idx = blockIdx.x * 256 + threadIdx.x;
    if (idx >= 3 * 128 * 128) return;
    int w = idx >> 14;
    int r = idx & 16383;
    int k = r >> 7, nn = r & 127;
    const float* W = (w == 0) ? W0 : (w == 1) ? W1 : W2;
    float v = W[k * 128 + nn];
    _Float16 hi = (_Float16)v;
    _Float16 lo = (_Float16)((v - (float)hi) * 1024.0f);
    int kk = k >> 5, quad = (k >> 3) & 3, j = k & 7;
    int t = nn >> 4, L = quad * 16 + (nn & 15);
    int off = ((kk * 8 + t) * 64 + L) * 8 + j;
    Wsw[(size_t)(w * 2 + 0) * 16384 + off] = hi;
    Wsw[(size_t)(w * 2 + 1) * 16384 + off] = lo;
}

// MFMA GEMM core (A fp16). Epilogue scales row by dinv[row]:
// C[i] = dinv[i] * (A[i] @ W). Block: 8 waves, 128 rows.
__global__ __launch_bounds__(512) void gemm_mfma(const _Float16* __restrict__ A,
                                                 const _Float16* __restrict__ Wsw,
                                                 const float* __restrict__ dinv,
                                                 _Float16* __restrict__ C, int n) {
    __shared__ _Float16 Bl[2 * 16384];
    {
        const uint4* s = (const uint4*)Wsw;
        uint4* d = (uint4*)Bl;
        for (int i = threadIdx.x; i < 4096; i += 512) d[i] = s[i];
    }
    int wave = threadIdx.x >> 6, lane = threadIdx.x & 63;
    int quad = lane >> 4, mcol = lane & 15;
    int row0 = blockIdx.x * 128 + wave * 16 + mcol;
    half8 af[4] = {};
    if (row0 < n) {
        const half8* Arow = (const half8*)(A + (size_t)row0 * DFEAT);
        af[0] = Arow[0 + quad];
        af[1] = Arow[4 + quad];
        af[2] = Arow[8 + quad];
        af[3] = Arow[12 + quad];
    }
    __syncthreads();
    floatx4 acch[8] = {};
    floatx4 accl[8] = {};
    const half8* Bh = (const half8*)Bl;
    const half8* Blo = (const half8*)(Bl + 16384);
    #pragma unroll
    for (int kk = 0; kk < 4; kk++) {
        #pragma unroll
        for (int t = 0; t < 8; t++) {
            half8 bh = Bh[(kk * 8 + t) * 64 + lane];
            acch[t] = __builtin_amdgcn_mfma_f32_16x16x32_f16(af[kk], bh, acch[t], 0, 0, 0);
            half8 bl = Blo[(kk * 8 + t) * 64 + lane];
            accl[t] = __builtin_amdgcn_mfma_f32_16x16x32_f16(af[kk], bl, accl[t], 0, 0, 0);
        }
    }
    int orow_base = blockIdx.x * 128 + wave * 16 + quad * 4;
    float dv[4];
    #pragma unroll
    for (int r = 0; r < 4; r++)
        dv[r] = (orow_base + r < n) ? dinv[orow_base + r] : 0.f;
    #pragma unroll
    for (int t = 0; t < 8; t++) {
        #pragma unroll
        for (int r = 0; r < 4; r++) {
            int orow = orow_base + r;
            if (orow < n) {
                float v = (acch[t][r] + accl[t][r] * (1.0f / 1024.0f)) * dv[r];
                C[(size_t)orow * DFEAT + t * 16 + mcol] = (_Float16)v;
            }
        }
    }
}

// Same, but reads fp32 A (layer 0: x directly).
__global__ __launch_bounds__(512) void gemm_mfma_f32(const float* __restrict__ A,
                                                     const _Float16* __restrict__ Wsw,
                                                     const float* __restrict__ dinv,
                                                     _Float16* __restrict__ C, int n) {
    __shared__ _Float16 Bl[2 * 16384];
    {
        const uint4* s = (const uint4*)Wsw;
        uint4* d = (uint4*)Bl;
        for (int i = threadIdx.x; i < 4096; i += 512) d[i] = s[i];
    }
    int wave = threadIdx.x >> 6, lane = threadIdx.x & 63;
    int quad = lane >> 4, mcol = lane & 15;
    int row0 = blockIdx.x * 128 + wave * 16 + mcol;
    half8 af[4] = {};
    if (row0 < n) {
        const float4* Arow = (const float4*)(A + (size_t)row0 * DFEAT);
        #pragma unroll
        for (int kk = 0; kk < 4; kk++) {
            float4 f0 = Arow[kk * 8 + quad * 2];
            float4 f1 = Arow[kk * 8 + quad * 2 + 1];
            half8 a;
            a[0] = (_Float16)f0.x; a[1] = (_Float16)f0.y;
            a[2] = (_Float16)f0.z; a[3] = (_Float16)f0.w;
            a[4] = (_Float16)f1.x; a[5] = (_Float16)f1.y;
            a[6] = (_Float16)f1.z; a[7] = (_Float16)f1.w;
            af[kk] = a;
        }
    }
    __syncthreads();
    floatx4 acch[8] = {};
    floatx4 accl[8] = {};
    const half8* Bh = (const half8*)Bl;
    const half8* Blo = (const half8*)(Bl + 16384);
    #pragma unroll
    for (int kk = 0; kk < 4; kk++) {
        #pragma unroll
        for (int t = 0; t < 8; t++) {
            half8 bh = Bh[(kk * 8 + t) * 64 + lane];
            acch[t] = __builtin_amdgcn_mfma_f32_16x16x32_f16(af[kk], bh, acch[t], 0, 0, 0);
            half8 bl = Blo[(kk * 8 + t) * 64 + lane];
            accl[t] = __builtin_amdgcn_mfma_f32_16x16x32_f16(af[kk], bl, accl[t], 0, 0, 0);
        }
    }
    int orow_base = blockIdx.x * 128 + wave * 16 + quad * 4;
    float dv[4];
    #pragma unroll
    for (int r = 0; r < 4; r++)
        dv[r] = (orow_base + r < n) ? dinv[orow_base + r] : 0.f;
    #pragma unroll
    for (int t = 0; t < 8; t++) {
        #pragma unroll
        for (int r = 0; r < 4; r++) {
            int orow = orow_base + r;
            if (orow < n) {
                float v = (acch[t][r] + accl[t][r] * (1.0f / 1024.0f)) * dv[r];
                C[(size_t)orow * DFEAT + t * 16 + mcol] = (_Float16)v;
            }
        }
    }
}

// 4 nodes per 256-thread block (one wave each); lane holds 2 fp16 features.
// xw is pre-scaled by dinv (gemm epilogue): msg = (ew*dinv_d) * xw'[src];
// self term = dinv_d * xw'[node].
__global__ __launch_bounds__(256) void agg_k(const __half2* __restrict__ xw2,
                                             const int* __restrict__ rp8,
                                             const unsigned* __restrict__ csr,
                                             const float* __restrict__ dinv,
                                             const float* __restrict__ bias,
                                             __half2* __restrict__ out, int relu, int n) {
    int node = blockIdx.x * 4 + (threadIdx.x >> 6);
    if (node >= n) return;
    int lane = threadIdx.x & 63;
    float di = dinv[node];
    float2 selfv = __half22float2(xw2[(size_t)node * 64 + lane]);
    float ax = di * selfv.x, ay = di * selfv.y;
    int e = rp8[node * NPART], end = rp8[node * NPART + NPART];
    for (; e + 4 <= end; e += 4) {
        unsigned c0 = csr[e + 0], c1 = csr[e + 1];
        unsigned c2 = csr[e + 2], c3 = csr[e + 3];
        float2 v0 = __half22float2(xw2[(size_t)(c0 & 0xffff) * 64 + lane]);
        float2 v1 = __half22float2(xw2[(size_t)(c1 & 0xffff) * 64 + lane]);
        float2 v2 = __half22float2(xw2[(size_t)(c2 & 0xffff) * 64 + lane]);
        float2 v3 = __half22float2(xw2[(size_t)(c3 & 0xffff) * 64 + lane]);
        float w0 = __half2float(__ushort_as_half((unsigned short)(c0 >> 16)));
        float w1 = __half2float(__ushort_as_half((unsigned short)(c1 >> 16)));
        float w2 = __half2float(__ushort_as_half((unsigned short)(c2 >> 16)));
        float w3 = __half2float(__ushort_as_half((unsigned short)(c3 >> 16)));
        ax = fmaf(w0, v0.x, ax); ay = fmaf(w0, v0.y, ay);
        ax = fmaf(w1, v1.x, ax); ay = fmaf(w1, v1.y, ay);
        ax = fmaf(w2, v2.x, ax); ay = fmaf(w2, v2.y, ay);
        ax = fmaf(w3, v3.x, ax); ay = fmaf(w3, v3.y, ay);
    }
    for (; e < end; e++) {
        unsigned c = csr[e];
        float w = __half2float(__ushort_as_half((unsigned short)(c >> 16)));
        float2 v = __half22float2(xw2[(size_t)(c & 0xffff) * 64 + lane]);
        ax = fmaf(w, v.x, ax); ay = fmaf(w, v.y, ay);
    }
    float2 bv = ((const float2*)bias)[lane];
    ax += bv.x; ay += bv.y;
    if (relu) { ax = fmaxf(ax, 0.f); ay = fmaxf(ay, 0.f); }
    out[(size_t)node * 64 + lane] = __floats2half2_rn(ax, ay);
}

// batch is sorted: chunk of 64 nodes per block, 128 threads (one per feature).
__global__ __launch_bounds__(128) void pool_k(const __half* __restrict__ h,
                                              const int* __restrict__ batch,
                                              float* __restrict__ out,
                                              float* __restrict__ pool_cnt, int n) {
    int j = threadIdx.x;
    int start = blockIdx.x * 64;
    if (start >= n) return;
    int end = start + 64; if (end > n) end = n;
    int g = batch[start];
    float acc = 0.f;
    float ccnt = 0.f;
    for (int i = start; i < end; i++) {
        int bi = batch[i];
        if (bi != g) {
            atomicAdd(&out[g * DFEAT + j], acc);
            if (j == 0) atomicAdd(&pool_cnt[g], ccnt);
            acc = 0.f; ccnt = 0.f; g = bi;
        }
        acc += __half2float(h[(size_t)i * DFEAT + j]);
        ccnt += 1.f;
    }
    atomicAdd(&out[g * DFEAT + j], acc);
    if (j == 0) atomicAdd(&pool_cnt[g], ccnt);
}

__global__ void div_k(float* __restrict__ out, const float* __restrict__ cnt) {
    int idx = blockIdx.x * 256 + threadIdx.x;
    if (idx < 64 * DFEAT) {
        float c = cnt[idx >> 7];
        out[idx] = out[idx] / fmaxf(c, 1.0f);
    }
}

extern "C" void kernel_launch(void* const* d_in, const int* in_sizes, int n_in,
                              void* d_out, int out_size, void* d_ws, size_t ws_size,
                              hipStream_t stream) {
    const float* x    = (const float*)d_in[0];
    const int*  eidx  = (const int*)d_in[1];
    const float* ew   = (const float*)d_in[2];
    const int*  batch = (const int*)d_in[3];
    const float* W0 = (const float*)d_in[4];
    const float* b0 = (const float*)d_in[5];
    const float* W1 = (const float*)d_in[6];
    const float* b1 = (const float*)d_in[7];
    const float* W2 = (const float*)d_in[8];
    const float* b2 = (const float*)d_in[9];
    float* out = (float*)d_out;

    const int N = in_sizes[0] / DFEAT;   // 50000 (must be <= 65536)
    const int E = in_sizes[2];           // 1600000
    const int* src = eidx;
    const int* dst = eidx + E;

    const int nbuck = (N + 255) / 256;           // 196
    const int nblk  = (E + BLK_E - 1) / BLK_E;   // 391
    const int total = nbuck * nblk;
    const int n_scan = total + 1;                // sentinel -> E

    size_t off = 0;
    auto walloc = [&](size_t bytes) -> void* {
        void* p = (char*)d_ws + off;
        off += (bytes + 255) & ~(size_t)255;
        return p;
    };
    float*   dinv    = (float*)  walloc((size_t)N * 4);
    int*     rp8     = (int*)    walloc(((size_t)nbuck * 2048 + 8) * 4);
    int*     offs    = (int*)    walloc((size_t)n_scan * 4);
    int*     blksum  = (int*)    walloc(256 * 4);
    uint2*   rec     = (uint2*)  walloc((size_t)E * 8);
    unsigned* csr    = (unsigned*)walloc((size_t)E * 4);
    _Float16* xwH    = (_Float16*)walloc((size_t)N * DFEAT * 2);
    _Float16* hH     = (_Float16*)walloc((size_t)N * DFEAT * 2);
    _Float16* Wsw    = (_Float16*)walloc((size_t)6 * 16384 * 2);
    float*   pool_cnt= (float*)  walloc(64 * 4);

    (void)hipMemsetAsync(out, 0, (size_t)64 * DFEAT * 4, stream);
    (void)hipMemsetAsync(pool_cnt, 0, 64 * 4, stream);

    // ---- CSR build (no global atomics, no normfix) ----
    hist_k<<<nblk, 256, 0, stream>>>(dst, offs, E, nblk, nbuck);
    int nsb = (n_scan + 1023) / 1024;
    scanb_k<<<nsb, 256, 0, stream>>>(offs, blksum, total, n_scan);
    scan_small256<<<1, 256, 0, stream>>>(blksum, nsb);
    scat_k<<<nblk, 256, 0, stream>>>(src, dst, ew, offs, blksum, rec, E, nblk, nbuck);
    bucket_k<<<nbuck, 1024, 0, stream>>>(rec, offs, blksum, dinv, rp8, csr, N, nblk);

    wconv_k<<<(3 * 16384 + 255) / 256, 256, 0, stream>>>(W0, W1, W2, Wsw);

    int gG = (N + 127) / 128;
    int gA = (N + 3) / 4;
    // layer 0 (reads fp32 x directly)
    gemm_mfma_f32<<<gG, 512, 0, stream>>>(x, Wsw + (size_t)0 * 32768, dinv, xwH, N);
    agg_k<<<gA, 256, 0, stream>>>((const __half2*)xwH, rp8, csr, dinv, b0,
                                  (__half2*)hH, 1, N);
    // layer 1
    gemm_mfma<<<gG, 512, 0, stream>>>(hH, Wsw + (size_t)1 * 32768, dinv, xwH, N);
    agg_k<<<gA, 256, 0, stream>>>((const __half2*)xwH, rp8, csr, dinv, b1,
                                  (__half2*)hH, 1, N);
    // layer 2
    gemm_mfma<<<gG, 512, 0, stream>>>(hH, Wsw + (size_t)2 * 32768, dinv, xwH, N);
    agg_k<<<gA, 256, 0, stream>>>((const __half2*)xwH, rp8, csr, dinv, b2,
                                  (__half2*)hH, 0, N);

    pool_k<<<(N + 63) / 64, 128, 0, stream>>>((const __half*)hH, batch, out, pool_cnt, N);
    div_k<<<32, 256, 0, stream>>>(out, pool_cnt);
}

// Round 13
// 372.971 us; speedup vs baseline: 1.0712x; 1.0398x over previous
//
#include <hip/hip_runtime.h>
#include <hip/hip_fp16.h>

// ---------------------------------------------------------------------------
// GCNEncoder: 3x GCNConv(128->128) + ReLU(2x) + global mean pool (64 graphs)
//   - CSR build, ZERO global atomics (two-level counting sort).
//   - dinv[src] folded into GEMM epilogue (xw' = dinv*xw); csr = 4B
//     {src:u16, fp16(ew*dinv_dst)} finalized inside bucket_k.
//   - agg_k at the L2-miss/fabric service floor (FETCH ~1.4x compulsory;
//     R6/R8/R11 attack vectors all neutral). No NT hints (R11 lesson).
//   - hist_k fused with wconv + output zeroing (3 fewer dispatches);
//     scat_k at 512 threads for intra-block parallelism.
// ---------------------------------------------------------------------------

#define DFEAT 128
#define BLK_E 4096   // edges per sort block
#define NPART 8

typedef _Float16 half8 __attribute__((ext_vector_type(8)));
typedef float floatx4 __attribute__((ext_vector_type(4)));

__device__ __forceinline__ int wave_incl_scan(int v) {
    int incl = v;
    #pragma unroll
    for (int off = 1; off < 64; off <<= 1) {
        int u = __shfl_up(incl, (unsigned)off, 64);
        if ((int)(threadIdx.x & 63) >= off) incl += u;
    }
    return incl;
}

__device__ __forceinline__ void wconv_elem(int idx, const float* __restrict__ W0,
                                           const float* __restrict__ W1,
                                           const float* __restrict__ W2,
                                           _Float16* __restrict__ Wsw) {
    if (idx >= 3 * 128 * 128) return;
    int w = idx >> 14;
    int r = idx & 16383;
    int k = r >> 7, nn = r & 127;
    const float* W = (w == 0) ? W0 : (w == 1) ? W1 : W2;
    float v = W[k * 128 + nn];
    _Float16 hi = (_Float16)v;
    _Float16 lo = (_Float16)((v - (float)hi) * 1024.0f);
    int kk = k >> 5, quad = (k >> 3) & 3, j = k & 7;
    int t = nn >> 4, L = quad * 16 + (nn & 15);
    int off = ((kk * 8 + t) * 64 + L) * 8 + j;
    Wsw[(size_t)(w * 2 + 0) * 16384 + off] = hi;
    Wsw[(size_t)(w * 2 + 1) * 16384 + off] = lo;
}

// K1: per-block histogram over coarse buckets (dst >> 8), bin-major output.
// Fused side work: blocks 0..47 convert/swizzle W (1024 elems each);
// blocks 0..7 zero `out` (1024 floats each); block 8 zeros pool_cnt.
__global__ __launch_bounds__(256) void hist_k(const int* __restrict__ dst,
                                              int* __restrict__ hist,
                                              const float* __restrict__ W0,
                                              const float* __restrict__ W1,
                                              const float* __restrict__ W2,
                                              _Float16* __restrict__ Wsw,
                                              float* __restrict__ out,
                                              float* __restrict__ pool_cnt,
                                              int E, int nblk, int nbuck) {
    __shared__ int h[256];
    int tid = threadIdx.x, b = blockIdx.x;
    h[tid] = 0;
    // fused side work (no barrier interaction; independent outputs)
    if (b < 48) {
        #pragma unroll
        for (int k = 0; k < 4; k++)
            wconv_elem(b * 1024 + k * 256 + tid, W0, W1, W2, Wsw);
    }
    if (b < 8) {
        floatx4 z = {0.f, 0.f, 0.f, 0.f};
        ((floatx4*)out)[b * 256 + tid] = z;   // 8 blocks x 256 x 4 = 8192
    }
    if (b == 8 && tid < 64) pool_cnt[tid] = 0.f;
    __syncthreads();
    int base = b * BLK_E;
    int nE = min(BLK_E, E - base);
    for (int i = tid; i < nE; i += 256) atomicAdd(&h[dst[base + i] >> 8], 1);
    __syncthreads();
    if (tid < nbuck) hist[tid * nblk + b] = h[tid];
}

// Block-local exclusive scan, 1024 elems/block, in-place; blksum = totals.
__global__ __launch_bounds__(256) void scanb_k(int* __restrict__ arr,
                                               int* __restrict__ blksum,
                                               int n_val, int n_scan) {
    int tid = threadIdx.x;
    int base = blockIdx.x * 1024 + tid * 4;
    int v0 = (base + 0 < n_val) ? arr[base + 0] : 0;
    int v1 = (base + 1 < n_val) ? arr[base + 1] : 0;
    int v2 = (base + 2 < n_val) ? arr[base + 2] : 0;
    int v3 = (base + 3 < n_val) ? arr[base + 3] : 0;
    int tsum = v0 + v1 + v2 + v3;
    int incl = wave_incl_scan(tsum);
    __shared__ int wtot[4];
    if ((tid & 63) == 63) wtot[tid >> 6] = incl;
    __syncthreads();
    int woff = 0;
    for (int w = 0; w < (tid >> 6); w++) woff += wtot[w];
    int texcl = woff + incl - tsum;
    if (base + 0 < n_scan) arr[base + 0] = texcl;
    if (base + 1 < n_scan) arr[base + 1] = texcl + v0;
    if (base + 2 < n_scan) arr[base + 2] = texcl + v0 + v1;
    if (base + 3 < n_scan) arr[base + 3] = texcl + v0 + v1 + v2;
    if (tid == 255) blksum[blockIdx.x] = woff + incl;
}

__global__ __launch_bounds__(256) void scan_small256(int* __restrict__ blksum, int nb) {
    int tid = threadIdx.x;
    int v = (tid < nb) ? blksum[tid] : 0;
    int incl = wave_incl_scan(v);
    __shared__ int wtot[4];
    if ((tid & 63) == 63) wtot[tid >> 6] = incl;
    __syncthreads();
    int woff = 0;
    for (int w = 0; w < (tid >> 6); w++) woff += wtot[w];
    if (tid < nb) blksum[tid] = woff + incl - v;
}

// K3: scatter edges into bucket-grouped array, coalesced via LDS sort.
// rec = {src | dstlow<<16, ew_bits}. Requires N <= 65536. 512 threads.
__global__ __launch_bounds__(512) void scat_k(const int* __restrict__ src,
                                              const int* __restrict__ dst,
                                              const float* __restrict__ ew,
                                              const int* __restrict__ offs,
                                              const int* __restrict__ blksum,
                                              uint2* __restrict__ rec,
                                              int E, int nblk, int nbuck) {
    __shared__ int lcur[256];
    __shared__ int gbase[256];
    __shared__ uint2 srec[BLK_E];
    __shared__ int gpos[BLK_E];
    __shared__ int wtot[4];
    int tid = threadIdx.x, b = blockIdx.x;
    if (tid < 256) lcur[tid] = 0;
    __syncthreads();
    int base = b * BLK_E;
    int nE = min(BLK_E, E - base);
    for (int i = tid; i < nE; i += 512) atomicAdd(&lcur[dst[base + i] >> 8], 1);
    __syncthreads();
    int v = 0, incl = 0;
    if (tid < 256) { v = lcur[tid]; incl = wave_incl_scan(v); }
    if (tid < 256 && (tid & 63) == 63) wtot[tid >> 6] = incl;
    __syncthreads();
    if (tid < 256) {
        int woff = 0;
        for (int w = 0; w < (tid >> 6); w++) woff += wtot[w];
        int excl = woff + incl - v;
        lcur[tid] = excl;
        int oidx = tid * nblk + b;
        gbase[tid] = (tid < nbuck) ? (offs[oidx] + blksum[oidx >> 10] - excl) : 0;
    }
    __syncthreads();
    for (int i = tid; i < nE; i += 512) {
        int e = base + i;
        int d = dst[e];
        int bin = d >> 8;
        int slot = atomicAdd(&lcur[bin], 1);
        uint2 r;
        r.x = (unsigned)src[e] | ((unsigned)(d & 255) << 16);
        r.y = __float_as_uint(ew[e]);
        srec[slot] = r;
        gpos[slot] = gbase[bin] + slot;
    }
    __syncthreads();
    for (int i = tid; i < nE; i += 512) rec[gpos[i]] = srec[i];
}

// K4: one block per 256-node bucket. Per-(node, src>>13) counts + fixed-point
// deg in LDS, 2048-wide scan -> rp8 segment offsets + dinv, then place FINAL
// 4B CSR entries {src:u16, fp16(ew*dinv_dst)} grouped by src partition.
__global__ __launch_bounds__(1024) void bucket_k(const uint2* __restrict__ rec,
                                                 const int* __restrict__ offs,
                                                 const int* __restrict__ blksum,
                                                 float* __restrict__ dinv,
                                                 int* __restrict__ rp8,
                                                 unsigned* __restrict__ csr,
                                                 int N, int nblk) {
    __shared__ int cnt[2048];       // key = dl*8 + (src>>13)
    __shared__ unsigned degfx[256];
    __shared__ int cur[2048];
    __shared__ int wtot[16];
    int tid = threadIdx.x, bin = blockIdx.x;
    int idx0 = bin * nblk, idx1 = (bin + 1) * nblk;
    int start = offs[idx0] + blksum[idx0 >> 10];
    int endp  = offs[idx1] + blksum[idx1 >> 10];  // sentinel -> E for last bin
    cnt[tid] = 0; cnt[tid + 1024] = 0;
    if (tid < 256) degfx[tid] = 0;
    __syncthreads();
    for (int i = start + tid; i < endp; i += 1024) {
        uint2 r = rec[i];
        int dl = (r.x >> 16) & 255;
        int part = (r.x & 0xffff) >> 13;
        atomicAdd(&cnt[dl * NPART + part], 1);
        atomicAdd(&degfx[dl], (unsigned)(__uint_as_float(r.y) * 1048576.0f + 0.5f));
    }
    __syncthreads();
    int v0 = cnt[tid * 2], v1 = cnt[tid * 2 + 1];
    int tsum = v0 + v1;
    int incl = wave_incl_scan(tsum);
    if ((tid & 63) == 63) wtot[tid >> 6] = incl;
    __syncthreads();
    int woff = 0;
    for (int w = 0; w < (tid >> 6); w++) woff += wtot[w];
    int texcl = woff + incl - tsum;
    cur[tid * 2] = texcl;
    cur[tid * 2 + 1] = texcl + v0;
    // nodes >= N in the tail bucket have zero counts -> their rp8 slots get
    // the bucket end offset, which serves as the sentinel for node N-1.
    rp8[bin * 2048 + tid * 2] = start + texcl;
    rp8[bin * 2048 + tid * 2 + 1] = start + texcl + v0;
    __syncthreads();
    if (tid < 256) {
        int node = bin * 256 + tid;
        if (node < N) {
            float deg = (float)degfx[tid] * (1.0f / 1048576.0f) + 1.0f;
            float di = rsqrtf(deg);
            dinv[node] = di;
            degfx[tid] = __float_as_uint(di);   // stash dinv
        }
    }
    __syncthreads();
    for (int i = start + tid; i < endp; i += 1024) {
        uint2 r = rec[i];
        int dl = (r.x >> 16) & 255;
        int s = r.x & 0xffff;
        int part = s >> 13;
        int p = start + atomicAdd(&cur[dl * NPART + part], 1);
        float di_d = __uint_as_float(degfx[dl]);
        float nm = __uint_as_float(r.y) * di_d;   // ew * dinv_dst (final)
        unsigned h = (unsigned)__half_as_ushort(__float2half_rn(nm));
        csr[p] = (unsigned)s | (h << 16);
    }
}

// MFMA GEMM core (A fp16). Epilogue scales row by dinv[row]:
// C[i] = dinv[i] * (A[i] @ W). Block: 8 waves, 128 rows.
__global__ __launch_bounds__(512) void gemm_mfma(const _Float16* __restrict__ A,
                                                 const _Float16* __restrict__ Wsw,
                                                 const float* __restrict__ dinv,
                                                 _Float16* __restrict__ C, int n) {
    __shared__ _Float16 Bl[2 * 16384];
    {
        const uint4* s = (const uint4*)Wsw;
        uint4* d = (uint4*)Bl;
        for (int i = threadIdx.x; i < 4096; i += 512) d[i] = s[i];
    }
    int wave = threadIdx.x >> 6, lane = threadIdx.x & 63;
    int quad = lane >> 4, mcol = lane & 15;
    int row0 = blockIdx.x * 128 + wave * 16 + mcol;
    half8 af[4] = {};
    if (row0 < n) {
        const half8* Arow = (const half8*)(A + (size_t)row0 * DFEAT);
        af[0] = Arow[0 + quad];
        af[1] = Arow[4 + quad];
        af[2] = Arow[8 + quad];
        af[3] = Arow[12 + quad];
    }
    __syncthreads();
    floatx4 acch[8] = {};
    floatx4 accl[8] = {};
    const half8* Bh = (const half8*)Bl;
    const half8* Blo = (const half8*)(Bl + 16384);
    #pragma unroll
    for (int kk = 0; kk < 4; kk++) {
        #pragma unroll
        for (int t = 0; t < 8; t++) {
            half8 bh = Bh[(kk * 8 + t) * 64 + lane];
            acch[t] = __builtin_amdgcn_mfma_f32_16x16x32_f16(af[kk], bh, acch[t], 0, 0, 0);
            half8 bl = Blo[(kk * 8 + t) * 64 + lane];
            accl[t] = __builtin_amdgcn_mfma_f32_16x16x32_f16(af[kk], bl, accl[t], 0, 0, 0);
        }
    }
    int orow_base = blockIdx.x * 128 + wave * 16 + quad * 4;
    float dv[4];
    #pragma unroll
    for (int r = 0; r < 4; r++)
        dv[r] = (orow_base + r < n) ? dinv[orow_base + r] : 0.f;
    #pragma unroll
    for (int t = 0; t < 8; t++) {
        #pragma unroll
        for (int r = 0; r < 4; r++) {
            int orow = orow_base + r;
            if (orow < n) {
                float v = (acch[t][r] + accl[t][r] * (1.0f / 1024.0f)) * dv[r];
                C[(size_t)orow * DFEAT + t * 16 + mcol] = (_Float16)v;
            }
        }
    }
}

// Same, but reads fp32 A (layer 0: x directly).
__global__ __launch_bounds__(512) void gemm_mfma_f32(const float* __restrict__ A,
                                                     const _Float16* __restrict__ Wsw,
                                                     const float* __restrict__ dinv,
                                                     _Float16* __restrict__ C, int n) {
    __shared__ _Float16 Bl[2 * 16384];
    {
        const uint4* s = (const uint4*)Wsw;
        uint4* d = (uint4*)Bl;
        for (int i = threadIdx.x; i < 4096; i += 512) d[i] = s[i];
    }
    int wave = threadIdx.x >> 6, lane = threadIdx.x & 63;
    int quad = lane >> 4, mcol = lane & 15;
    int row0 = blockIdx.x * 128 + wave * 16 + mcol;
    half8 af[4] = {};
    if (row0 < n) {
        const float4* Arow = (const float4*)(A + (size_t)row0 * DFEAT);
        #pragma unroll
        for (int kk = 0; kk < 4; kk++) {
            float4 f0 = Arow[kk * 8 + quad * 2];
            float4 f1 = Arow[kk * 8 + quad * 2 + 1];
            half8 a;
            a[0] = (_Float16)f0.x; a[1] = (_Float16)f0.y;
            a[2] = (_Float16)f0.z; a[3] = (_Float16)f0.w;
            a[4] = (_Float16)f1.x; a[5] = (_Float16)f1.y;
            a[6] = (_Float16)f1.z; a[7] = (_Float16)f1.w;
            af[kk] = a;
        }
    }
    __syncthreads();
    floatx4 acch[8] = {};
    floatx4 accl[8] = {};
    const half8* Bh = (const half8*)Bl;
    const half8* Blo = (const half8*)(Bl + 16384);
    #pragma unroll
    for (int kk = 0; kk < 4; kk++) {
        #pragma unroll
        for (int t = 0; t < 8; t++) {
            half8 bh = Bh[(kk * 8 + t) * 64 + lane];
            acch[t] = __builtin_amdgcn_mfma_f32_16x16x32_f16(af[kk], bh, acch[t], 0, 0, 0);
            half8 bl = Blo[(kk * 8 + t) * 64 + lane];
            accl[t] = __builtin_amdgcn_mfma_f32_16x16x32_f16(af[kk], bl, accl[t], 0, 0, 0);
        }
    }
    int orow_base = blockIdx.x * 128 + wave * 16 + quad * 4;
    float dv[4];
    #pragma unroll
    for (int r = 0; r < 4; r++)
        dv[r] = (orow_base + r < n) ? dinv[orow_base + r] : 0.f;
    #pragma unroll
    for (int t = 0; t < 8; t++) {
        #pragma unroll
        for (int r = 0; r < 4; r++) {
            int orow = orow_base + r;
            if (orow < n) {
                float v = (acch[t][r] + accl[t][r] * (1.0f / 1024.0f)) * dv[r];
                C[(size_t)orow * DFEAT + t * 16 + mcol] = (_Float16)v;
            }
        }
    }
}

// 4 nodes per 256-thread block (one wave each); lane holds 2 fp16 features.
__global__ __launch_bounds__(256) void agg_k(const __half2* __restrict__ xw2,
                                             const int* __restrict__ rp8,
                                             const unsigned* __restrict__ csr,
                                             const float* __restrict__ dinv,
                                             const float* __restrict__ bias,
                                             __half2* __restrict__ out, int relu, int n) {
    int node = blockIdx.x * 4 + (threadIdx.x >> 6);
    if (node >= n) return;
    int lane = threadIdx.x & 63;
    float di = dinv[node];
    float2 selfv = __half22float2(xw2[(size_t)node * 64 + lane]);
    float ax = di * selfv.x, ay = di * selfv.y;
    int e = rp8[node * NPART], end = rp8[node * NPART + NPART];
    for (; e + 4 <= end; e += 4) {
        unsigned c0 = csr[e + 0], c1 = csr[e + 1];
        unsigned c2 = csr[e + 2], c3 = csr[e + 3];
        float2 v0 = __half22float2(xw2[(size_t)(c0 & 0xffff) * 64 + lane]);
        float2 v1 = __half22float2(xw2[(size_t)(c1 & 0xffff) * 64 + lane]);
        float2 v2 = __half22float2(xw2[(size_t)(c2 & 0xffff) * 64 + lane]);
        float2 v3 = __half22float2(xw2[(size_t)(c3 & 0xffff) * 64 + lane]);
        float w0 = __half2float(__ushort_as_half((unsigned short)(c0 >> 16)));
        float w1 = __half2float(__ushort_as_half((unsigned short)(c1 >> 16)));
        float w2 = __half2float(__ushort_as_half((unsigned short)(c2 >> 16)));
        float w3 = __half2float(__ushort_as_half((unsigned short)(c3 >> 16)));
        ax = fmaf(w0, v0.x, ax); ay = fmaf(w0, v0.y, ay);
        ax = fmaf(w1, v1.x, ax); ay = fmaf(w1, v1.y, ay);
        ax = fmaf(w2, v2.x, ax); ay = fmaf(w2, v2.y, ay);
        ax = fmaf(w3, v3.x, ax); ay = fmaf(w3, v3.y, ay);
    }
    for (; e < end; e++) {
        unsigned c = csr[e];
        float w = __half2float(__ushort_as_half((unsigned short)(c >> 16)));
        float2 v = __half22float2(xw2[(size_t)(c & 0xffff) * 64 + lane]);
        ax = fmaf(w, v.x, ax); ay = fmaf(w, v.y, ay);
    }
    float2 bv = ((const float2*)bias)[lane];
    ax += bv.x; ay += bv.y;
    if (relu) { ax = fmaxf(ax, 0.f); ay = fmaxf(ay, 0.f); }
    out[(size_t)node * 64 + lane] = __floats2half2_rn(ax, ay);
}

// batch is sorted: chunk of 64 nodes per block, 128 threads (one per feature).
__global__ __launch_bounds__(128) void pool_k(const __half* __restrict__ h,
                                              const int* __restrict__ batch,
                                              float* __restrict__ out,
                                              float* __restrict__ pool_cnt, int n) {
    int j = threadIdx.x;
    int start = blockIdx.x * 64;
    if (start >= n) return;
    int end = start + 64; if (end > n) end = n;
    int g = batch[start];
    float acc = 0.f;
    float ccnt = 0.f;
    for (int i = start; i < end; i++) {
        int bi = batch[i];
        if (bi != g) {
            atomicAdd(&out[g * DFEAT + j], acc);
            if (j == 0) atomicAdd(&pool_cnt[g], ccnt);
            acc = 0.f; ccnt = 0.f; g = bi;
        }
        acc += __half2float(h[(size_t)i * DFEAT + j]);
        ccnt += 1.f;
    }
    atomicAdd(&out[g * DFEAT + j], acc);
    if (j == 0) atomicAdd(&pool_cnt[g], ccnt);
}

__global__ void div_k(float* __restrict__ out, const float* __restrict__ cnt) {
    int idx = blockIdx.x * 256 + threadIdx.x;
    if (idx < 64 * DFEAT) {
        float c = cnt[idx >> 7];
        out[idx] = out[idx] / fmaxf(c, 1.0f);
    }
}

extern "C" void kernel_launch(void* const* d_in, const int* in_sizes, int n_in,
                              void* d_out, int out_size, void* d_ws, size_t ws_size,
                              hipStream_t stream) {
    const float* x    = (const float*)d_in[0];
    const int*  eidx  = (const int*)d_in[1];
    const float* ew   = (const float*)d_in[2];
    const int*  batch = (const int*)d_in[3];
    const float* W0 = (const float*)d_in[4];
    const float* b0 = (const float*)d_in[5];
    const float* W1 = (const float*)d_in[6];
    const float* b1 = (const float*)d_in[7];
    const float* W2 = (const float*)d_in[8];
    const float* b2 = (const float*)d_in[9];
    float* out = (float*)d_out;

    const int N = in_sizes[0] / DFEAT;   // 50000 (must be <= 65536)
    const int E = in_sizes[2];           // 1600000
    const int* src = eidx;
    const int* dst = eidx + E;

    const int nbuck = (N + 255) / 256;           // 196
    const int nblk  = (E + BLK_E - 1) / BLK_E;   // 391
    const int total = nbuck * nblk;
    const int n_scan = total + 1;                // sentinel -> E

    size_t off = 0;
    auto walloc = [&](size_t bytes) -> void* {
        void* p = (char*)d_ws + off;
        off += (bytes + 255) & ~(size_t)255;
        return p;
    };
    float*   dinv    = (float*)  walloc((size_t)N * 4);
    int*     rp8     = (int*)    walloc(((size_t)nbuck * 2048 + 8) * 4);
    int*     offs    = (int*)    walloc((size_t)n_scan * 4);
    int*     blksum  = (int*)    walloc(256 * 4);
    uint2*   rec     = (uint2*)  walloc((size_t)E * 8);
    unsigned* csr    = (unsigned*)walloc((size_t)E * 4);
    _Float16* xwH    = (_Float16*)walloc((size_t)N * DFEAT * 2);
    _Float16* hH     = (_Float16*)walloc((size_t)N * DFEAT * 2);
    _Float16* Wsw    = (_Float16*)walloc((size_t)6 * 16384 * 2);
    float*   pool_cnt= (float*)  walloc(64 * 4);

    // ---- CSR build (no global atomics); hist fused with wconv + zeroing ----
    hist_k<<<nblk, 256, 0, stream>>>(dst, offs, W0, W1, W2, Wsw, out, pool_cnt,
                                     E, nblk, nbuck);
    int nsb = (n_scan + 1023) / 1024;
    scanb_k<<<nsb, 256, 0, stream>>>(offs, blksum, total, n_scan);
    scan_small256<<<1, 256, 0, stream>>>(blksum, nsb);
    scat_k<<<nblk, 512, 0, stream>>>(src, dst, ew, offs, blksum, rec, E, nblk, nbuck);
    bucket_k<<<nbuck, 1024, 0, stream>>>(rec, offs, blksum, dinv, rp8, csr, N, nblk);

    int gG = (N + 127) / 128;
    int gA = (N + 3) / 4;
    // layer 0 (reads fp32 x directly)
    gemm_mfma_f32<<<gG, 512, 0, stream>>>(x, Wsw + (size_t)0 * 32768, dinv, xwH, N);
    agg_k<<<gA, 256, 0, stream>>>((const __half2*)xwH, rp8, csr, dinv, b0,
                                  (__half2*)hH, 1, N);
    // layer 1
    gemm_mfma<<<gG, 512, 0, stream>>>(hH, Wsw + (size_t)1 * 32768, dinv, xwH, N);
    agg_k<<<gA, 256, 0, stream>>>((const __half2*)xwH, rp8, csr, dinv, b1,
                                  (__half2*)hH, 1, N);
    // layer 2
    gemm_mfma<<<gG, 512, 0, stream>>>(hH, Wsw + (size_t)2 * 32768, dinv, xwH, N);
    agg_k<<<gA, 256, 0, stream>>>((const __half2*)xwH, rp8, csr, dinv, b2,
                                  (__half2*)hH, 0, N);

    pool_k<<<(N + 63) / 64, 128, 0, stream>>>((const __half*)hH, batch, out, pool_cnt, N);
    div_k<<<32, 256, 0, stream>>>(out, pool_cnt);
}